// Round 8
// baseline (1692.389 us; speedup 1.0000x reference)
//
#include <hip/hip_runtime.h>
#include <hip/hip_bf16.h>

typedef __attribute__((ext_vector_type(4))) float f32x4;
typedef __attribute__((ext_vector_type(8))) short bf16x8;

#define B_    75
#define C_    640
#define HW_   441
#define NWAY_ 5
#define M_    2205
#define SHOTS_ 5
#define AV_   5

#define QT_ROWS 448     // 441 padded (zeros)
#define ST_ROWS 2304    // 2205 padded (zeros); reads reach 4*441+127 = 1891 (+srow)

// fp32 fallback-path tiling (round-2 kernel, kept as ws_size insurance)
#define XT    16
#define JB    256
#define CTILE 64

// ---------------- K1: inverse norms ----------------
__global__ void norms_kernel(const float* __restrict__ q, const float* __restrict__ S,
                             float* __restrict__ qinv, float* __restrict__ sinv) {
    int id = blockIdx.x * 256 + threadIdx.x;
    if (id < B_ * HW_) {
        int b = id / HW_, x = id % HW_;
        const float* p = q + (size_t)b * C_ * HW_ + x;
        float ss = 0.f;
        for (int c = 0; c < C_; ++c) { float v = p[(size_t)c * HW_]; ss += v * v; }
        qinv[id] = 1.0f / (sqrtf(ss) + 1e-8f);
    } else {
        int id2 = id - B_ * HW_;
        if (id2 < NWAY_ * M_) {
            int n = id2 / M_, m = id2 % M_;
            const float* p = S + (size_t)n * C_ * M_ + m;
            float ss = 0.f;
            for (int c = 0; c < C_; ++c) { float v = p[(size_t)c * M_]; ss += v * v; }
            sinv[id2] = 1.0f / (sqrtf(ss) + 1e-8f);
        }
    }
}

// ---------------- prep: transpose + normalize + bf16 ----------------
__global__ void prep_q(const float* __restrict__ q, const float* __restrict__ qinv,
                       ushort* __restrict__ qT) {
    __shared__ float tile[32][33];
    const int tx = threadIdx.x & 31, ty = threadIdx.x >> 5;
    const int x0 = blockIdx.x * 32, c0 = blockIdx.y * 32, b = blockIdx.z;
    #pragma unroll
    for (int i = 0; i < 4; ++i) {
        int c = c0 + ty + i * 8, x = x0 + tx;
        tile[ty + i * 8][tx] = (x < HW_) ? q[((size_t)b * C_ + c) * HW_ + x] : 0.f;
    }
    __syncthreads();
    #pragma unroll
    for (int i = 0; i < 4; ++i) {
        int xr = x0 + ty + i * 8, cc = c0 + tx;
        float w = 0.f;
        if (xr < HW_) w = tile[tx][ty + i * 8] * qinv[b * HW_ + xr];
        __hip_bfloat16 h = __float2bfloat16(w);
        qT[((size_t)b * QT_ROWS + xr) * C_ + cc] = *(ushort*)&h;
    }
}

__global__ void prep_s(const float* __restrict__ S, const float* __restrict__ sinv,
                       ushort* __restrict__ ST) {
    __shared__ float tile[32][33];
    const int tx = threadIdx.x & 31, ty = threadIdx.x >> 5;
    const int m0 = blockIdx.x * 32, c0 = blockIdx.y * 32, n = blockIdx.z;
    #pragma unroll
    for (int i = 0; i < 4; ++i) {
        int c = c0 + ty + i * 8, m = m0 + tx;
        tile[ty + i * 8][tx] = (m < M_) ? S[((size_t)n * C_ + c) * M_ + m] : 0.f;
    }
    __syncthreads();
    #pragma unroll
    for (int i = 0; i < 4; ++i) {
        int mr = m0 + ty + i * 8, cc = c0 + tx;
        float w = 0.f;
        if (mr < M_) w = tile[tx][ty + i * 8] * sinv[n * M_ + mr];
        __hip_bfloat16 h = __float2bfloat16(w);
        ST[((size_t)n * ST_ROWS + mr) * C_ + cc] = *(ushort*)&h;
    }
}

// sorted-top3 insert: t0 >= t1 >= t2
__device__ __forceinline__ void ins3(float v, float& t0, float& t1, float& t2) {
    t2 = fmaxf(t2, fminf(v, t1));
    t1 = fmaxf(t1, fminf(v, t0));
    t0 = fmaxf(t0, v);
}

// async global->LDS, 16B per lane. LDS dest = wave-uniform base + lane*16.
__device__ __forceinline__ void gload16(const void* g, void* l) {
    __builtin_amdgcn_global_load_lds(
        (const __attribute__((address_space(1))) void*)g,
        (__attribute__((address_space(3))) void*)l, 16, 0, 0);
}

// ---------------- main: bf16 MFMA GEMM + fused per-chunk top3 (v4) ----------------
// 128x128 tile, BK=64, 8 waves (2x4 grid, wave-tile 64x32), 512 threads.
// v3 -> v4: __launch_bounds__(512,4) -> (512,2). Second arg is min BLOCKS/CU
// (CUDA semantics, confirmed by v3's VGPR_Count=64 = 512/8-waves-EU): arg 4
// forced an 8-wave/EU register budget (64 VGPR) and ~120 live regs spilled
// (WRITE_SIZE 1.45 GB of scratch). arg 2 -> 4 waves/EU -> 128 VGPR cap.
__launch_bounds__(512, 2)
__global__ void knn_mfma(const ushort* __restrict__ qT, const ushort* __restrict__ ST,
                         float* __restrict__ cand) {
    __shared__ ushort Al[2][128 * 64];
    __shared__ ushort Bl[2][128 * 64];
    __shared__ float  mrg[4][128][3];

    const int tid = threadIdx.x;
    // bijective XCD chunking (m204): nwg=7500, q=937, r=4
    const int orig = blockIdx.x;
    const int xcd = orig & 7, idx = orig >> 3;
    int wg = (xcd < 4) ? xcd * 938 + idx : 3752 + (xcd - 4) * 937 + idx;
    // decode (n, s, b, xt): n slowest -> per-XCD chunk keeps one ST panel L2-hot
    const int n = wg / 1500;  int rem = wg - n * 1500;
    const int s = rem / 300;  rem -= s * 300;
    const int b  = rem >> 2;
    const int xt = rem & 3;
    const int x0 = (xt < 3) ? xt * 128 : 320;   // tile 3 overlaps (rows 320-447)

    const int lane = tid & 63, wid = tid >> 6;   // wid 0..7
    const int wm = wid >> 2, wn = wid & 3;       // 2x4 wave grid, wave-tile 64x32
    const int l15 = lane & 15, l4 = lane >> 4;

    const ushort* qbase = qT + ((size_t)b * QT_ROWS + x0) * C_;
    const ushort* sbase = ST + ((size_t)n * ST_ROWS + s * HW_) * C_;

    // staging: 512 threads x 16B = half a 16KB tile per round; 2 rounds/operand.
    const int srow  = tid >> 3;    // = wid*8 + (lane>>3); +64 on round 1
    const int sslot = tid & 7;     // linear 16B slot within row

    auto STAGE = [&](int pbuf, int pjt, int pc0) {
        #pragma unroll
        for (int i = 0; i < 2; ++i) {
            const int rb = (wid << 3) + (i << 6);       // wave-uniform row base
            const int r  = srow + (i << 6);             // this lane's row
            const int cs = sslot ^ (r & 7);             // inverse-swizzled source slot
            gload16(qbase + (size_t)r * C_ + pc0 + cs * 8, &Al[pbuf][rb * 64]);
            gload16(sbase + ((size_t)pjt * 128 + r) * C_ + pc0 + cs * 8, &Bl[pbuf][rb * 64]);
        }
    };

    float t0a[16], t1a[16], t2a[16];
    #pragma unroll
    for (int i = 0; i < 16; ++i) { t0a[i] = -2.f; t1a[i] = -2.f; t2a[i] = -2.f; }

    STAGE(0, 0, 0);
    int buf = 0;

    #pragma unroll 1
    for (int jt = 0; jt < 4; ++jt) {
        f32x4 acc[4][2];
        #pragma unroll
        for (int mi = 0; mi < 4; ++mi)
            #pragma unroll
            for (int ni = 0; ni < 2; ++ni) acc[mi][ni] = (f32x4)(0.f);

        #pragma unroll 1
        for (int kt = 0; kt < 10; ++kt) {
            __builtin_amdgcn_s_barrier();            // trail: all waves done reading buf^1
            if (jt == 3 && kt == 9) {
                asm volatile("s_waitcnt vmcnt(0)" ::: "memory");
            } else {
                const int jt1 = (kt == 9) ? jt + 1 : jt;
                const int kt1 = (kt == 9) ? 0 : kt + 1;
                STAGE(buf ^ 1, jt1, kt1 * 64);       // prefetch next tile (4 loads)
                asm volatile("s_waitcnt vmcnt(4)" ::: "memory");  // cur tile (4 oldest) done
            }
            __builtin_amdgcn_s_barrier();            // head: cur tile visible to all
            __builtin_amdgcn_sched_barrier(0);
            #pragma unroll
            for (int ks = 0; ks < 2; ++ks) {
                bf16x8 af[4], bg[2];
                #pragma unroll
                for (int mi = 0; mi < 4; ++mi) {
                    const int row = wm * 64 + mi * 16 + l15;
                    af[mi] = *(const bf16x8*)&Al[buf][row * 64 + ((ks * 4 + l4) ^ (row & 7)) * 8];
                }
                #pragma unroll
                for (int ni = 0; ni < 2; ++ni) {
                    const int row = wn * 32 + ni * 16 + l15;
                    bg[ni] = *(const bf16x8*)&Bl[buf][row * 64 + ((ks * 4 + l4) ^ (row & 7)) * 8];
                }
                #pragma unroll
                for (int mi = 0; mi < 4; ++mi)
                    #pragma unroll
                    for (int ni = 0; ni < 2; ++ni)
                        acc[mi][ni] = __builtin_amdgcn_mfma_f32_16x16x32_bf16(
                            af[mi], bg[ni], acc[mi][ni], 0, 0, 0);
            }
            buf ^= 1;
        }

        // fused epilogue (register-only): running per-row top3
        if (jt < 3) {
            #pragma unroll
            for (int mi = 0; mi < 4; ++mi)
                #pragma unroll
                for (int ni = 0; ni < 2; ++ni)
                    #pragma unroll
                    for (int r = 0; r < 4; ++r) {
                        const int ridx = mi * 4 + r;
                        ins3(acc[mi][ni][r], t0a[ridx], t1a[ridx], t2a[ridx]);
                    }
        } else {   // last col-tile: mask cols >= 441 (next-chunk bleed + ST pad)
            float bias[2];
            #pragma unroll
            for (int ni = 0; ni < 2; ++ni)
                bias[ni] = (384 + wn * 32 + ni * 16 + l15 < HW_) ? 0.f : -8.f;
            #pragma unroll
            for (int mi = 0; mi < 4; ++mi)
                #pragma unroll
                for (int ni = 0; ni < 2; ++ni)
                    #pragma unroll
                    for (int r = 0; r < 4; ++r) {
                        const int ridx = mi * 4 + r;
                        ins3(acc[mi][ni][r] + bias[ni], t0a[ridx], t1a[ridx], t2a[ridx]);
                    }
        }
    }

    // cross-lane butterfly over the 16 column-lanes (bits 0-3 of lane)
    #pragma unroll
    for (int st = 1; st <= 8; st <<= 1) {
        #pragma unroll
        for (int ridx = 0; ridx < 16; ++ridx) {
            float o0 = __shfl_xor(t0a[ridx], st);
            float o1 = __shfl_xor(t1a[ridx], st);
            float o2 = __shfl_xor(t2a[ridx], st);
            ins3(o0, t0a[ridx], t1a[ridx], t2a[ridx]);
            ins3(o1, t0a[ridx], t1a[ridx], t2a[ridx]);
            ins3(o2, t0a[ridx], t1a[ridx], t2a[ridx]);
        }
    }
    // one lane per 16-lane group publishes its 16 rows' triples
    if (l15 == 0) {
        #pragma unroll
        for (int mi = 0; mi < 4; ++mi)
            #pragma unroll
            for (int r = 0; r < 4; ++r) {
                const int rowl = wm * 64 + mi * 16 + l4 * 4 + r;
                const int ridx = mi * 4 + r;
                mrg[wn][rowl][0] = t0a[ridx];
                mrg[wn][rowl][1] = t1a[ridx];
                mrg[wn][rowl][2] = t2a[ridx];
            }
    }
    __syncthreads();
    if (tid < 128) {
        float a0 = mrg[0][tid][0], a1 = mrg[0][tid][1], a2 = mrg[0][tid][2];
        #pragma unroll
        for (int w = 1; w < 4; ++w) {
            ins3(mrg[w][tid][0], a0, a1, a2);
            ins3(mrg[w][tid][1], a0, a1, a2);
            ins3(mrg[w][tid][2], a0, a1, a2);
        }
        const int x = x0 + tid;
        if (x < HW_) {
            size_t base = ((size_t)((b * NWAY_ + n) * SHOTS_ + s) * HW_ + x) * 3;
            cand[base] = a0; cand[base + 1] = a1; cand[base + 2] = a2;
        }
    }
}

// ---------------- fallback fp32 GEMM (ws_size insurance) --------
__launch_bounds__(256, 2)
__global__ void knn_main(const float* __restrict__ q, const float* __restrict__ S,
                         const float* __restrict__ qinv, const float* __restrict__ sinv,
                         float* __restrict__ cand) {
    __shared__ float smem[CTILE * JB];
    __shared__ float s_q[CTILE * 20];
    __shared__ float run3[XT * 3];
    const int tid = threadIdx.x;
    const int xt = blockIdx.x, ns = blockIdx.y, b = blockIdx.z;
    const int n = ns / SHOTS_, s = ns % SHOTS_;
    const int x0 = xt * XT;
    const int xg = tid & 3, jg = tid >> 2;
    if (tid < XT * 3) run3[tid] = -2.0f;
    const float* qb = q + (size_t)b * C_ * HW_;
    const float* Sc = S + (size_t)n * C_ * M_ + s * HW_;
    for (int jb = 0; jb < 2; ++jb) {
        const int j0 = jb * JB;
        float acc[4][4];
        #pragma unroll
        for (int xi = 0; xi < 4; ++xi)
            #pragma unroll
            for (int ji = 0; ji < 4; ++ji) acc[xi][ji] = 0.f;
        for (int ct = 0; ct < C_ / CTILE; ++ct) {
            const int c0 = ct * CTILE;
            for (int idx = tid; idx < CTILE * XT; idx += 256) {
                int c = idx >> 4, xl = idx & 15;
                int xglob = x0 + xl;
                s_q[c * 20 + xl] = (xglob < HW_) ? qb[(size_t)(c0 + c) * HW_ + xglob] : 0.f;
            }
            for (int idx = tid; idx < CTILE * JB; idx += 256) {
                int c = idx >> 8, j = idx & 255;
                int jj = j0 + j;
                smem[idx] = (jj < HW_) ? Sc[(size_t)(c0 + c) * M_ + jj] : 0.f;
            }
            __syncthreads();
            #pragma unroll 16
            for (int c = 0; c < CTILE; ++c) {
                float4 qv = *(const float4*)&s_q[c * 20 + 4 * xg];
                float4 sv = *(const float4*)&smem[c * JB + 4 * jg];
                float qa[4] = {qv.x, qv.y, qv.z, qv.w};
                float sa[4] = {sv.x, sv.y, sv.z, sv.w};
                #pragma unroll
                for (int xi = 0; xi < 4; ++xi)
                    #pragma unroll
                    for (int ji = 0; ji < 4; ++ji)
                        acc[xi][ji] = fmaf(qa[xi], sa[ji], acc[xi][ji]);
            }
            __syncthreads();
        }
        #pragma unroll
        for (int xi = 0; xi < 4; ++xi) {
            const int xglob = x0 + 4 * xg + xi;
            const float qv = (xglob < HW_) ? qinv[b * HW_ + xglob] : 0.f;
            float t0 = -2.f, t1 = -2.f, t2 = -2.f;
            #pragma unroll
            for (int ji = 0; ji < 4; ++ji) {
                const int jj = j0 + 4 * jg + ji;
                if (jj < HW_) {
                    float v = acc[xi][ji] * qv * sinv[n * M_ + s * HW_ + jj];
                    ins3(v, t0, t1, t2);
                }
            }
            const int xl = 4 * xg + xi;
            smem[xl * 193 + jg * 3 + 0] = t0;
            smem[xl * 193 + jg * 3 + 1] = t1;
            smem[xl * 193 + jg * 3 + 2] = t2;
        }
        __syncthreads();
        if (tid < XT) {
            float r0 = run3[tid * 3], r1 = run3[tid * 3 + 1], r2 = run3[tid * 3 + 2];
            for (int i = 0; i < 64 * 3; ++i) ins3(smem[tid * 193 + i], r0, r1, r2);
            run3[tid * 3] = r0; run3[tid * 3 + 1] = r1; run3[tid * 3 + 2] = r2;
        }
        __syncthreads();
    }
    if (tid < XT) {
        int xglob = x0 + tid;
        if (xglob < HW_) {
            size_t base = ((size_t)((b * NWAY_ + n) * SHOTS_ + s) * HW_ + xglob) * 3;
            cand[base] = run3[tid * 3]; cand[base + 1] = run3[tid * 3 + 1]; cand[base + 2] = run3[tid * 3 + 2];
        }
    }
}

// ---------------- reduce + final ----------------
__global__ void reduce_kernel(const float* __restrict__ cand,
                              float* __restrict__ is_ws, float* __restrict__ cs_ws) {
    __shared__ float red[512];
    const int bn = blockIdx.x;
    const int tid = threadIdx.x;
    float outv[6] = {0, 0, 0, 0, 0, 0};
    if (tid < HW_) {
        float t0 = -2.f, t1 = -2.f, t2 = -2.f;
        #pragma unroll
        for (int s = 0; s < SHOTS_; ++s) {
            size_t base = ((size_t)(bn * SHOTS_ + s) * HW_ + tid) * 3;
            float v0 = cand[base], v1 = cand[base + 1], v2 = cand[base + 2];
            outv[1 + s] = v0 + v1 + v2;
            ins3(v0, t0, t1, t2); ins3(v1, t0, t1, t2); ins3(v2, t0, t1, t2);
        }
        outv[0] = t0 + t1 + t2;
    }
    for (int qi = 0; qi < 6; ++qi) {
        red[tid] = outv[qi];
        __syncthreads();
        for (int st = 256; st > 0; st >>= 1) {
            if (tid < st) red[tid] += red[tid + st];
            __syncthreads();
        }
        if (tid == 0) {
            if (qi == 0) is_ws[bn] = red[0];
            else         cs_ws[bn * SHOTS_ + qi - 1] = red[0];
        }
        __syncthreads();
    }
}

__global__ void final_kernel(const float* __restrict__ is_ws, const float* __restrict__ cs_ws,
                             float* __restrict__ out) {
    int tid = threadIdx.x;
    if (tid < 75) {
        int g = tid / NWAY_, n = tid % NWAY_;
        float a = 0.f;
        #pragma unroll
        for (int av = 0; av < AV_; ++av) a += logf(is_ws[(g * AV_ + av) * NWAY_ + n]);
        out[tid] = expf(a * 0.2f);
    } else if (tid < 450) {
        int u = tid - 75;
        int g = u / 25, n = (u / 5) % 5, s = u % 5;
        float a = 0.f;
        #pragma unroll
        for (int av = 0; av < AV_; ++av)
            a += logf(fmaxf(cs_ws[((g * AV_ + av) * NWAY_ + n) * SHOTS_ + s], 1e-8f));
        out[75 + u] = expf(a * 0.2f);
    }
}

extern "C" void kernel_launch(void* const* d_in, const int* in_sizes, int n_in,
                              void* d_out, int out_size, void* d_ws, size_t ws_size,
                              hipStream_t stream) {
    const float* q = (const float*)d_in[0];
    const float* S = (const float*)d_in[1];
    float* ws = (float*)d_ws;
    // float-region layout
    float* qinv = ws;                               // 33075
    float* sinv = ws + 33075;                       // 11025
    float* cand = ws + 44100;                       // 2,480,625
    float* isw  = ws + 2524725;                     // 375
    float* csw  = ws + 2525100;                     // 1875
    // bf16 region, 16B-aligned at byte 10,107,904
    ushort* qT = (ushort*)d_ws + 5053952;           // 75*448*640 = 21,504,000
    ushort* STb = (ushort*)d_ws + 26557952;         // 5*2304*640 = 7,372,800
    const size_t NEED = (26557952ull + 7372800ull) * 2ull;   // 67,861,504 B
    float* out = (float*)d_out;

    norms_kernel<<<(B_ * HW_ + NWAY_ * M_ + 255) / 256, 256, 0, stream>>>(q, S, qinv, sinv);
    if (ws_size >= NEED) {
        dim3 gq(QT_ROWS / 32, C_ / 32, B_);         // (14,20,75)
        prep_q<<<gq, 256, 0, stream>>>(q, qinv, qT);
        dim3 gs(ST_ROWS / 32, C_ / 32, NWAY_);      // (72,20,5)
        prep_s<<<gs, 256, 0, stream>>>(S, sinv, STb);
        knn_mfma<<<7500, 512, 0, stream>>>(qT, STb, cand);
    } else {
        dim3 grid((HW_ + XT - 1) / XT, NWAY_ * SHOTS_, B_);
        knn_main<<<grid, 256, 0, stream>>>(q, S, qinv, sinv, cand);
    }
    reduce_kernel<<<B_ * NWAY_, 512, 0, stream>>>(cand, isw, csw);
    final_kernel<<<1, 512, 0, stream>>>(isw, csw, out);
}

// Round 9
// 993.472 us; speedup vs baseline: 1.7035x; 1.7035x over previous
//
#include <hip/hip_runtime.h>
#include <hip/hip_bf16.h>

typedef __attribute__((ext_vector_type(4))) float f32x4;
typedef __attribute__((ext_vector_type(8))) short bf16x8;

#define B_    75
#define C_    640
#define HW_   441
#define NWAY_ 5
#define M_    2205
#define SHOTS_ 5
#define AV_   5

#define QT_ROWS 448     // 441 padded (zeros)
#define ST_ROWS 2304    // 2205 padded (zeros)

// fp32 fallback-path tiling (round-2 kernel, kept as ws_size insurance)
#define XT    16
#define JB    256
#define CTILE 64

// ---------------- K1: inverse norms ----------------
__global__ void norms_kernel(const float* __restrict__ q, const float* __restrict__ S,
                             float* __restrict__ qinv, float* __restrict__ sinv) {
    int id = blockIdx.x * 256 + threadIdx.x;
    if (id < B_ * HW_) {
        int b = id / HW_, x = id % HW_;
        const float* p = q + (size_t)b * C_ * HW_ + x;
        float ss = 0.f;
        for (int c = 0; c < C_; ++c) { float v = p[(size_t)c * HW_]; ss += v * v; }
        qinv[id] = 1.0f / (sqrtf(ss) + 1e-8f);
    } else {
        int id2 = id - B_ * HW_;
        if (id2 < NWAY_ * M_) {
            int n = id2 / M_, m = id2 % M_;
            const float* p = S + (size_t)n * C_ * M_ + m;
            float ss = 0.f;
            for (int c = 0; c < C_; ++c) { float v = p[(size_t)c * M_]; ss += v * v; }
            sinv[id2] = 1.0f / (sqrtf(ss) + 1e-8f);
        }
    }
}

// ---------------- prep: transpose + normalize + bf16 ----------------
__global__ void prep_q(const float* __restrict__ q, const float* __restrict__ qinv,
                       ushort* __restrict__ qT) {
    __shared__ float tile[32][33];
    const int tx = threadIdx.x & 31, ty = threadIdx.x >> 5;
    const int x0 = blockIdx.x * 32, c0 = blockIdx.y * 32, b = blockIdx.z;
    #pragma unroll
    for (int i = 0; i < 4; ++i) {
        int c = c0 + ty + i * 8, x = x0 + tx;
        tile[ty + i * 8][tx] = (x < HW_) ? q[((size_t)b * C_ + c) * HW_ + x] : 0.f;
    }
    __syncthreads();
    #pragma unroll
    for (int i = 0; i < 4; ++i) {
        int xr = x0 + ty + i * 8, cc = c0 + tx;
        float w = 0.f;
        if (xr < HW_) w = tile[tx][ty + i * 8] * qinv[b * HW_ + xr];
        __hip_bfloat16 h = __float2bfloat16(w);
        qT[((size_t)b * QT_ROWS + xr) * C_ + cc] = *(ushort*)&h;
    }
}

__global__ void prep_s(const float* __restrict__ S, const float* __restrict__ sinv,
                       ushort* __restrict__ ST) {
    __shared__ float tile[32][33];
    const int tx = threadIdx.x & 31, ty = threadIdx.x >> 5;
    const int m0 = blockIdx.x * 32, c0 = blockIdx.y * 32, n = blockIdx.z;
    #pragma unroll
    for (int i = 0; i < 4; ++i) {
        int c = c0 + ty + i * 8, m = m0 + tx;
        tile[ty + i * 8][tx] = (m < M_) ? S[((size_t)n * C_ + c) * M_ + m] : 0.f;
    }
    __syncthreads();
    #pragma unroll
    for (int i = 0; i < 4; ++i) {
        int mr = m0 + ty + i * 8, cc = c0 + tx;
        float w = 0.f;
        if (mr < M_) w = tile[tx][ty + i * 8] * sinv[n * M_ + mr];
        __hip_bfloat16 h = __float2bfloat16(w);
        ST[((size_t)n * ST_ROWS + mr) * C_ + cc] = *(ushort*)&h;
    }
}

// sorted-top3 insert: t0 >= t1 >= t2
__device__ __forceinline__ void ins3(float v, float& t0, float& t1, float& t2) {
    t2 = fmaxf(t2, fminf(v, t1));
    t1 = fmaxf(t1, fminf(v, t0));
    t0 = fmaxf(t0, v);
}

// async global->LDS, 16B per lane. LDS dest = wave-uniform base + lane*16.
__device__ __forceinline__ void gload16(const void* g, void* l) {
    __builtin_amdgcn_global_load_lds(
        (const __attribute__((address_space(1))) void*)g,
        (__attribute__((address_space(3))) void*)l, 16, 0, 0);
}

// ---------------- main: bf16 MFMA GEMM + fused per-chunk top3 (v5) ----------------
// EXACT round-6 kernel (best measured: 932us, 256 thr, 2 blocks/CU) with ONE
// change: block-index decode order. Round-6 decode (n slowest) made the ~64
// concurrent blocks/XCD span 64 distinct 160KB q-panels (10MB >> 4MB L2) ->
// the jt loop's 4x q-panel re-stage missed L2 -> FETCH 2.2GB ~= dur*BW
// (HBM-fetch-bound). New decode: 15 groups of 5 b's; order (bg, ns, b_in, xt)
// -> concurrent blocks share a 5x4-panel q set (3.2MB, L2-hot) while one
// 2.7MB S-panel streams. Expected FETCH ~0.4-0.8GB.
__launch_bounds__(256, 2)
__global__ void knn_mfma(const ushort* __restrict__ qT, const ushort* __restrict__ ST,
                         float* __restrict__ cand) {
    __shared__ ushort Al[2][128 * 64];
    __shared__ ushort Bl[2][128 * 64];
    __shared__ float  mrg[2][128][3];

    const int tid = threadIdx.x;
    // bijective XCD chunking (m204): nwg=7500, q=937, r=4
    const int orig = blockIdx.x;
    const int xcd = orig & 7, idx = orig >> 3;
    int wg = (xcd < 4) ? xcd * 938 + idx : 3752 + (xcd - 4) * 937 + idx;
    // decode (bg, ns, b_in, xt): b-group of 5 slowest, ns next, (b_in, xt) fast
    const int bg = wg / 500;  int rem = wg - bg * 500;
    const int ns = rem / 20;  rem -= ns * 20;
    const int b  = bg * 5 + (rem >> 2);
    const int xt = rem & 3;
    const int n = ns / SHOTS_, s = ns % SHOTS_;
    const int x0 = (xt < 3) ? xt * 128 : 320;   // tile 3 overlaps (rows 320-447)

    const int lane = tid & 63, wid = tid >> 6;
    const int wm = wid >> 1, wn = wid & 1;
    const int l15 = lane & 15, l4 = lane >> 4;

    const ushort* qbase = qT + ((size_t)b * QT_ROWS + x0) * C_;
    const ushort* sbase = ST + ((size_t)n * ST_ROWS + s * HW_) * C_;

    // staging geometry: wave stages rows [wid*32, wid*32+32), 4 instrs x 8 rows.
    const int srow8 = (wid << 5) + (lane >> 3);   // + i*8
    const int sslot = lane & 7;                   // linear 16B slot within row

    auto STAGE = [&](int pbuf, int pjt, int pc0) {
        #pragma unroll
        for (int i = 0; i < 4; ++i) {
            const int rb = (wid << 5) + (i << 3);       // wave-uniform row base
            const int r  = srow8 + (i << 3);            // this lane's row
            const int cs = sslot ^ (r & 7);             // inverse-swizzled source slot
            gload16(qbase + (size_t)r * C_ + pc0 + cs * 8, &Al[pbuf][rb * 64]);
            gload16(sbase + ((size_t)pjt * 128 + r) * C_ + pc0 + cs * 8, &Bl[pbuf][rb * 64]);
        }
    };

    float t0a[16], t1a[16], t2a[16];
    #pragma unroll
    for (int i = 0; i < 16; ++i) { t0a[i] = -2.f; t1a[i] = -2.f; t2a[i] = -2.f; }

    STAGE(0, 0, 0);
    int buf = 0;

    #pragma unroll 1
    for (int jt = 0; jt < 4; ++jt) {
        f32x4 acc[4][4];
        #pragma unroll
        for (int mi = 0; mi < 4; ++mi)
            #pragma unroll
            for (int ni = 0; ni < 4; ++ni) acc[mi][ni] = (f32x4)(0.f);

        #pragma unroll 1
        for (int kt = 0; kt < 10; ++kt) {
            __builtin_amdgcn_s_barrier();            // trail: all waves done reading buf^1
            if (jt == 3 && kt == 9) {
                asm volatile("s_waitcnt vmcnt(0)" ::: "memory");
            } else {
                const int jt1 = (kt == 9) ? jt + 1 : jt;
                const int kt1 = (kt == 9) ? 0 : kt + 1;
                STAGE(buf ^ 1, jt1, kt1 * 64);       // prefetch next tile
                asm volatile("s_waitcnt vmcnt(8)" ::: "memory");  // cur tile (8 oldest) done
            }
            __builtin_amdgcn_s_barrier();            // head: cur tile visible to all
            __builtin_amdgcn_sched_barrier(0);
            #pragma unroll
            for (int ks = 0; ks < 2; ++ks) {
                bf16x8 af[4], bg4[4];
                #pragma unroll
                for (int mi = 0; mi < 4; ++mi) {
                    const int row = wm * 64 + mi * 16 + l15;
                    af[mi] = *(const bf16x8*)&Al[buf][row * 64 + ((ks * 4 + l4) ^ (row & 7)) * 8];
                }
                #pragma unroll
                for (int ni = 0; ni < 4; ++ni) {
                    const int row = wn * 64 + ni * 16 + l15;
                    bg4[ni] = *(const bf16x8*)&Bl[buf][row * 64 + ((ks * 4 + l4) ^ (row & 7)) * 8];
                }
                #pragma unroll
                for (int mi = 0; mi < 4; ++mi)
                    #pragma unroll
                    for (int ni = 0; ni < 4; ++ni)
                        acc[mi][ni] = __builtin_amdgcn_mfma_f32_16x16x32_bf16(
                            af[mi], bg4[ni], acc[mi][ni], 0, 0, 0);
            }
            buf ^= 1;
        }

        // fused epilogue (register-only): running per-row top3
        if (jt < 3) {
            #pragma unroll
            for (int mi = 0; mi < 4; ++mi)
                #pragma unroll
                for (int ni = 0; ni < 4; ++ni)
                    #pragma unroll
                    for (int r = 0; r < 4; ++r) {
                        const int ridx = mi * 4 + r;
                        ins3(acc[mi][ni][r], t0a[ridx], t1a[ridx], t2a[ridx]);
                    }
        } else {   // last col-tile: mask cols >= 441 (next-chunk bleed + ST pad)
            float bias[4];
            #pragma unroll
            for (int ni = 0; ni < 4; ++ni)
                bias[ni] = (384 + wn * 64 + ni * 16 + l15 < HW_) ? 0.f : -8.f;
            #pragma unroll
            for (int mi = 0; mi < 4; ++mi)
                #pragma unroll
                for (int ni = 0; ni < 4; ++ni)
                    #pragma unroll
                    for (int r = 0; r < 4; ++r) {
                        const int ridx = mi * 4 + r;
                        ins3(acc[mi][ni][r] + bias[ni], t0a[ridx], t1a[ridx], t2a[ridx]);
                    }
        }
    }

    // cross-lane butterfly over the 16 column-lanes (bits 0-3 of lane)
    #pragma unroll
    for (int st = 1; st <= 8; st <<= 1) {
        #pragma unroll
        for (int ridx = 0; ridx < 16; ++ridx) {
            float o0 = __shfl_xor(t0a[ridx], st);
            float o1 = __shfl_xor(t1a[ridx], st);
            float o2 = __shfl_xor(t2a[ridx], st);
            ins3(o0, t0a[ridx], t1a[ridx], t2a[ridx]);
            ins3(o1, t0a[ridx], t1a[ridx], t2a[ridx]);
            ins3(o2, t0a[ridx], t1a[ridx], t2a[ridx]);
        }
    }
    // one lane per 16-lane group publishes its 16 rows' triples
    if (l15 == 0) {
        #pragma unroll
        for (int mi = 0; mi < 4; ++mi)
            #pragma unroll
            for (int r = 0; r < 4; ++r) {
                const int rowl = wm * 64 + mi * 16 + l4 * 4 + r;
                const int ridx = mi * 4 + r;
                mrg[wn][rowl][0] = t0a[ridx];
                mrg[wn][rowl][1] = t1a[ridx];
                mrg[wn][rowl][2] = t2a[ridx];
            }
    }
    __syncthreads();
    if (tid < 128) {
        float a0 = mrg[0][tid][0], a1 = mrg[0][tid][1], a2 = mrg[0][tid][2];
        ins3(mrg[1][tid][0], a0, a1, a2);
        ins3(mrg[1][tid][1], a0, a1, a2);
        ins3(mrg[1][tid][2], a0, a1, a2);
        const int x = x0 + tid;
        if (x < HW_) {
            size_t base = ((size_t)((b * NWAY_ + n) * SHOTS_ + s) * HW_ + x) * 3;
            cand[base] = a0; cand[base + 1] = a1; cand[base + 2] = a2;
        }
    }
}

// ---------------- fallback fp32 GEMM (ws_size insurance) --------
__launch_bounds__(256, 2)
__global__ void knn_main(const float* __restrict__ q, const float* __restrict__ S,
                         const float* __restrict__ qinv, const float* __restrict__ sinv,
                         float* __restrict__ cand) {
    __shared__ float smem[CTILE * JB];
    __shared__ float s_q[CTILE * 20];
    __shared__ float run3[XT * 3];
    const int tid = threadIdx.x;
    const int xt = blockIdx.x, ns = blockIdx.y, b = blockIdx.z;
    const int n = ns / SHOTS_, s = ns % SHOTS_;
    const int x0 = xt * XT;
    const int xg = tid & 3, jg = tid >> 2;
    if (tid < XT * 3) run3[tid] = -2.0f;
    const float* qb = q + (size_t)b * C_ * HW_;
    const float* Sc = S + (size_t)n * C_ * M_ + s * HW_;
    for (int jb = 0; jb < 2; ++jb) {
        const int j0 = jb * JB;
        float acc[4][4];
        #pragma unroll
        for (int xi = 0; xi < 4; ++xi)
            #pragma unroll
            for (int ji = 0; ji < 4; ++ji) acc[xi][ji] = 0.f;
        for (int ct = 0; ct < C_ / CTILE; ++ct) {
            const int c0 = ct * CTILE;
            for (int idx = tid; idx < CTILE * XT; idx += 256) {
                int c = idx >> 4, xl = idx & 15;
                int xglob = x0 + xl;
                s_q[c * 20 + xl] = (xglob < HW_) ? qb[(size_t)(c0 + c) * HW_ + xglob] : 0.f;
            }
            for (int idx = tid; idx < CTILE * JB; idx += 256) {
                int c = idx >> 8, j = idx & 255;
                int jj = j0 + j;
                smem[idx] = (jj < HW_) ? Sc[(size_t)(c0 + c) * M_ + jj] : 0.f;
            }
            __syncthreads();
            #pragma unroll 16
            for (int c = 0; c < CTILE; ++c) {
                float4 qv = *(const float4*)&s_q[c * 20 + 4 * xg];
                float4 sv = *(const float4*)&smem[c * JB + 4 * jg];
                float qa[4] = {qv.x, qv.y, qv.z, qv.w};
                float sa[4] = {sv.x, sv.y, sv.z, sv.w};
                #pragma unroll
                for (int xi = 0; xi < 4; ++xi)
                    #pragma unroll
                    for (int ji = 0; ji < 4; ++ji)
                        acc[xi][ji] = fmaf(qa[xi], sa[ji], acc[xi][ji]);
            }
            __syncthreads();
        }
        #pragma unroll
        for (int xi = 0; xi < 4; ++xi) {
            const int xglob = x0 + 4 * xg + xi;
            const float qv = (xglob < HW_) ? qinv[b * HW_ + xglob] : 0.f;
            float t0 = -2.f, t1 = -2.f, t2 = -2.f;
            #pragma unroll
            for (int ji = 0; ji < 4; ++ji) {
                const int jj = j0 + 4 * jg + ji;
                if (jj < HW_) {
                    float v = acc[xi][ji] * qv * sinv[n * M_ + s * HW_ + jj];
                    ins3(v, t0, t1, t2);
                }
            }
            const int xl = 4 * xg + xi;
            smem[xl * 193 + jg * 3 + 0] = t0;
            smem[xl * 193 + jg * 3 + 1] = t1;
            smem[xl * 193 + jg * 3 + 2] = t2;
        }
        __syncthreads();
        if (tid < XT) {
            float r0 = run3[tid * 3], r1 = run3[tid * 3 + 1], r2 = run3[tid * 3 + 2];
            for (int i = 0; i < 64 * 3; ++i) ins3(smem[tid * 193 + i], r0, r1, r2);
            run3[tid * 3] = r0; run3[tid * 3 + 1] = r1; run3[tid * 3 + 2] = r2;
        }
        __syncthreads();
    }
    if (tid < XT) {
        int xglob = x0 + tid;
        if (xglob < HW_) {
            size_t base = ((size_t)((b * NWAY_ + n) * SHOTS_ + s) * HW_ + xglob) * 3;
            cand[base] = run3[tid * 3]; cand[base + 1] = run3[tid * 3 + 1]; cand[base + 2] = run3[tid * 3 + 2];
        }
    }
}

// ---------------- reduce + final ----------------
__global__ void reduce_kernel(const float* __restrict__ cand,
                              float* __restrict__ is_ws, float* __restrict__ cs_ws) {
    __shared__ float red[512];
    const int bn = blockIdx.x;
    const int tid = threadIdx.x;
    float outv[6] = {0, 0, 0, 0, 0, 0};
    if (tid < HW_) {
        float t0 = -2.f, t1 = -2.f, t2 = -2.f;
        #pragma unroll
        for (int s = 0; s < SHOTS_; ++s) {
            size_t base = ((size_t)(bn * SHOTS_ + s) * HW_ + tid) * 3;
            float v0 = cand[base], v1 = cand[base + 1], v2 = cand[base + 2];
            outv[1 + s] = v0 + v1 + v2;
            ins3(v0, t0, t1, t2); ins3(v1, t0, t1, t2); ins3(v2, t0, t1, t2);
        }
        outv[0] = t0 + t1 + t2;
    }
    for (int qi = 0; qi < 6; ++qi) {
        red[tid] = outv[qi];
        __syncthreads();
        for (int st = 256; st > 0; st >>= 1) {
            if (tid < st) red[tid] += red[tid + st];
            __syncthreads();
        }
        if (tid == 0) {
            if (qi == 0) is_ws[bn] = red[0];
            else         cs_ws[bn * SHOTS_ + qi - 1] = red[0];
        }
        __syncthreads();
    }
}

__global__ void final_kernel(const float* __restrict__ is_ws, const float* __restrict__ cs_ws,
                             float* __restrict__ out) {
    int tid = threadIdx.x;
    if (tid < 75) {
        int g = tid / NWAY_, n = tid % NWAY_;
        float a = 0.f;
        #pragma unroll
        for (int av = 0; av < AV_; ++av) a += logf(is_ws[(g * AV_ + av) * NWAY_ + n]);
        out[tid] = expf(a * 0.2f);
    } else if (tid < 450) {
        int u = tid - 75;
        int g = u / 25, n = (u / 5) % 5, s = u % 5;
        float a = 0.f;
        #pragma unroll
        for (int av = 0; av < AV_; ++av)
            a += logf(fmaxf(cs_ws[((g * AV_ + av) * NWAY_ + n) * SHOTS_ + s], 1e-8f));
        out[75 + u] = expf(a * 0.2f);
    }
}

extern "C" void kernel_launch(void* const* d_in, const int* in_sizes, int n_in,
                              void* d_out, int out_size, void* d_ws, size_t ws_size,
                              hipStream_t stream) {
    const float* q = (const float*)d_in[0];
    const float* S = (const float*)d_in[1];
    float* ws = (float*)d_ws;
    // float-region layout
    float* qinv = ws;                               // 33075
    float* sinv = ws + 33075;                       // 11025
    float* cand = ws + 44100;                       // 2,480,625
    float* isw  = ws + 2524725;                     // 375
    float* csw  = ws + 2525100;                     // 1875
    // bf16 region, 16B-aligned at byte 10,107,904
    ushort* qT = (ushort*)d_ws + 5053952;           // 75*448*640 = 21,504,000
    ushort* STb = (ushort*)d_ws + 26557952;         // 5*2304*640 = 7,372,800
    const size_t NEED = (26557952ull + 7372800ull) * 2ull;   // 67,861,504 B
    float* out = (float*)d_out;

    norms_kernel<<<(B_ * HW_ + NWAY_ * M_ + 255) / 256, 256, 0, stream>>>(q, S, qinv, sinv);
    if (ws_size >= NEED) {
        dim3 gq(QT_ROWS / 32, C_ / 32, B_);         // (14,20,75)
        prep_q<<<gq, 256, 0, stream>>>(q, qinv, qT);
        dim3 gs(ST_ROWS / 32, C_ / 32, NWAY_);      // (72,20,5)
        prep_s<<<gs, 256, 0, stream>>>(S, sinv, STb);
        knn_mfma<<<7500, 256, 0, stream>>>(qT, STb, cand);
    } else {
        dim3 grid((HW_ + XT - 1) / XT, NWAY_ * SHOTS_, B_);
        knn_main<<<grid, 256, 0, stream>>>(q, S, qinv, sinv, cand);
    }
    reduce_kernel<<<B_ * NWAY_, 512, 0, stream>>>(cand, isw, csw);
    final_kernel<<<1, 512, 0, stream>>>(isw, csw, out);
}